// Round 4
// baseline (517.579 us; speedup 1.0000x reference)
//
#include <hip/hip_runtime.h>
#include <hip/hip_bf16.h>
#include <stdint.h>

// ---------------------------------------------------------------------------
// SelfAttention (B=2,S=2048,D=1024,H=16,DK=64), fp32 in/out, bf16 MFMA inside.
// v3 (resubmit after infra timeout): fused QKV GEMM (8 waves), V transposed in
// GEMM epilogue, attention with direct-from-L2 K/Vt fragments, zero barriers,
// LDS only for the P exchange. Dispatches: cast3, cast4, gemm_qkv, attn, gemm_out.
// ---------------------------------------------------------------------------

typedef __bf16 bf16x8 __attribute__((ext_vector_type(8)));
typedef float f32x4 __attribute__((ext_vector_type(4)));

#define DEVI __device__ __forceinline__

static constexpr int S = 2048, D = 1024, H = 16, DK = 64, BATCH = 2;
static constexpr int BS = BATCH * S;  // 4096

DEVI void gload_lds16(const void* g, void* l) {
  __builtin_amdgcn_global_load_lds((const __attribute__((address_space(1))) void*)g,
                                   (__attribute__((address_space(3))) void*)l, 16, 0, 0);
}

// ---------------- casts ------------------------------------------------------
DEVI void cast8(const float* in, __bf16* out, int i) {
  float4 a = *(const float4*)(in + i);
  float4 b = *(const float4*)(in + i + 4);
  bf16x8 o;
  o[0] = (__bf16)a.x; o[1] = (__bf16)a.y; o[2] = (__bf16)a.z; o[3] = (__bf16)a.w;
  o[4] = (__bf16)b.x; o[5] = (__bf16)b.y; o[6] = (__bf16)b.z; o[7] = (__bf16)b.w;
  *(bf16x8*)(out + i) = o;
}

// 3 segments of BS*D elems (2048 blocks each)
__global__ void cast3(const float* s0, const float* s1, const float* s2,
                      __bf16* d0, __bf16* d1, __bf16* d2) {
  int seg = blockIdx.x >> 11;
  int i = (((blockIdx.x & 2047) << 8) + threadIdx.x) << 3;
  const float* s = seg == 0 ? s0 : seg == 1 ? s1 : s2;
  __bf16* d = seg == 0 ? d0 : seg == 1 ? d1 : d2;
  cast8(s, d, i);
}

// 4 segments of D*D elems (512 blocks each)
__global__ void cast4(const float* s0, const float* s1, const float* s2, const float* s3,
                      __bf16* d0, __bf16* d1, __bf16* d2, __bf16* d3) {
  int seg = blockIdx.x >> 9;
  int i = (((blockIdx.x & 511) << 8) + threadIdx.x) << 3;
  const float* s = seg == 0 ? s0 : seg == 1 ? s1 : seg == 2 ? s2 : s3;
  __bf16* d = seg == 0 ? d0 : seg == 1 ? d1 : seg == 2 ? d2 : d3;
  cast8(s, d, i);
}

// ---------------- fused QKV projection GEMM ---------------------------------
// grid (BS/128, 24): blockIdx.y -> segment (Q/K/V) * 8 column-tiles.
// 512 threads = 8 waves (2x4), tile 128x128, BK=64, m97 staging (linear LDS).
// Q: *NORM -> Qp;  K -> Kp;  V -> TRANSPOSED per-head store into Vt[b][h][dk][s2].
__global__ __launch_bounds__(512)
void gemm_qkv(const __bf16* __restrict__ xq, const __bf16* __restrict__ xk,
              const __bf16* __restrict__ xv, const __bf16* __restrict__ wqb,
              const __bf16* __restrict__ wkb, const __bf16* __restrict__ wvb,
              const float* __restrict__ bq, const float* __restrict__ bk,
              const float* __restrict__ bv, __bf16* __restrict__ Qp,
              __bf16* __restrict__ Kp, __bf16* __restrict__ Vt) {
  __shared__ __bf16 As[128 * 64];
  __shared__ __bf16 Bs[128 * 64];
  const int t = threadIdx.x, w = t >> 6;
  const int l = t & 63, c = l & 15, g = l >> 4;
  const int wr = w >> 2, wc = w & 3;
  const int m0 = blockIdx.x * 128;
  const int seg = blockIdx.y >> 3;
  const int n0 = (blockIdx.y & 7) * 128;  // within segment
  const __bf16* A = seg == 0 ? xq : seg == 1 ? xk : xv;
  const __bf16* W = seg == 0 ? wqb : seg == 1 ? wkb : wvb;
  const float* bias = seg == 0 ? bq : seg == 1 ? bk : bv;

  const int srow = t >> 3;          // 0..63
  const int scol = (t & 7) << 3;    // elems
  char* AsB = (char*)As;
  char* BsB = (char*)Bs;

  f32x4 acc[4][2] = {};

  for (int k0 = 0; k0 < D; k0 += 64) {
#pragma unroll
    for (int i = 0; i < 2; ++i) {
      gload_lds16(A + (size_t)(m0 + (i << 6) + srow) * D + k0 + scol, AsB + (i << 13) + (w << 10));
      gload_lds16(W + (size_t)(n0 + (i << 6) + srow) * D + k0 + scol, BsB + (i << 13) + (w << 10));
    }
    __syncthreads();
#pragma unroll
    for (int kf = 0; kf < 2; ++kf) {
      bf16x8 a[4], b[2];
#pragma unroll
      for (int mi = 0; mi < 4; ++mi)
        a[mi] = *(const bf16x8*)(AsB + ((wr << 6) + (mi << 4) + c) * 128 + (kf << 6) + (g << 4));
#pragma unroll
      for (int ni = 0; ni < 2; ++ni)
        b[ni] = *(const bf16x8*)(BsB + ((wc << 5) + (ni << 4) + c) * 128 + (kf << 6) + (g << 4));
#pragma unroll
      for (int mi = 0; mi < 4; ++mi)
#pragma unroll
        for (int ni = 0; ni < 2; ++ni)
          acc[mi][ni] = __builtin_amdgcn_mfma_f32_16x16x32_bf16(a[mi], b[ni], acc[mi][ni], 0, 0, 0);
    }
    __syncthreads();
  }

  // epilogue: C/D layout col=lane&15, row=(lane>>4)*4+r
  const float scale = (seg == 0) ? 0.125f : 1.0f;
#pragma unroll
  for (int ni = 0; ni < 2; ++ni) {
    const int col = n0 + (wc << 5) + (ni << 4) + c;  // within segment [0,1024)
    const float bvv = bias[col];
#pragma unroll
    for (int mi = 0; mi < 4; ++mi) {
#pragma unroll
      for (int r = 0; r < 4; ++r) {
        const int row = m0 + (wr << 6) + (mi << 4) + (g << 2) + r;
        const float v = (acc[mi][ni][r] + bvv) * scale;
        if (seg < 2) {
          __bf16* out = seg == 0 ? Qp : Kp;
          out[(size_t)row * D + col] = (__bf16)v;
        } else {
          // head-split transpose: f = (row&2047)*1024 + col
          const int so = row & 2047;
          const int b_ = row >> 11;
          const int h_ = so >> 7;
          const int s2 = ((so & 127) << 4) + (col >> 6);
          const int dk = col & 63;
          Vt[(((size_t)(b_ * H + h_) << 6) + dk) * S + s2] = (__bf16)v;
        }
      }
    }
  }
}

// ---------------- output projection GEMM (fp32 out) -------------------------
__global__ __launch_bounds__(512)
void gemm_out(const __bf16* __restrict__ A, const __bf16* __restrict__ W,
              const float* __restrict__ bias, float* __restrict__ out) {
  __shared__ __bf16 As[128 * 64];
  __shared__ __bf16 Bs[128 * 64];
  const int t = threadIdx.x, w = t >> 6;
  const int l = t & 63, c = l & 15, g = l >> 4;
  const int wr = w >> 2, wc = w & 3;
  const int m0 = blockIdx.x * 128, n0 = blockIdx.y * 128;
  const int srow = t >> 3;
  const int scol = (t & 7) << 3;
  char* AsB = (char*)As;
  char* BsB = (char*)Bs;

  f32x4 acc[4][2] = {};

  for (int k0 = 0; k0 < D; k0 += 64) {
#pragma unroll
    for (int i = 0; i < 2; ++i) {
      gload_lds16(A + (size_t)(m0 + (i << 6) + srow) * D + k0 + scol, AsB + (i << 13) + (w << 10));
      gload_lds16(W + (size_t)(n0 + (i << 6) + srow) * D + k0 + scol, BsB + (i << 13) + (w << 10));
    }
    __syncthreads();
#pragma unroll
    for (int kf = 0; kf < 2; ++kf) {
      bf16x8 a[4], b[2];
#pragma unroll
      for (int mi = 0; mi < 4; ++mi)
        a[mi] = *(const bf16x8*)(AsB + ((wr << 6) + (mi << 4) + c) * 128 + (kf << 6) + (g << 4));
#pragma unroll
      for (int ni = 0; ni < 2; ++ni)
        b[ni] = *(const bf16x8*)(BsB + ((wc << 5) + (ni << 4) + c) * 128 + (kf << 6) + (g << 4));
#pragma unroll
      for (int mi = 0; mi < 4; ++mi)
#pragma unroll
        for (int ni = 0; ni < 2; ++ni)
          acc[mi][ni] = __builtin_amdgcn_mfma_f32_16x16x32_bf16(a[mi], b[ni], acc[mi][ni], 0, 0, 0);
    }
    __syncthreads();
  }

#pragma unroll
  for (int ni = 0; ni < 2; ++ni) {
    const int col = n0 + (wc << 5) + (ni << 4) + c;
    const float bvv = bias[col];
#pragma unroll
    for (int mi = 0; mi < 4; ++mi)
#pragma unroll
      for (int r = 0; r < 4; ++r) {
        const int row = m0 + (wr << 6) + (mi << 4) + (g << 2) + r;
        out[(size_t)row * D + col] = acc[mi][ni][r] + bvv;
      }
  }
}

// ---------------- fused flash attention (no barriers) ------------------------
// grid (S/16, H/4, B), 256 threads; wave w = head blockIdx.y*4+w, q-rows [q0,q0+16).
// K/Vt fragments load DIRECTLY from global (L2-resident; each element used once
// per wave). LDS only for the P transpose exchange (wave-private, 5 KB/block).
__global__ void attn_fused(const __bf16* __restrict__ Qp, const __bf16* __restrict__ Kp,
                           const __bf16* __restrict__ Vt, const float* __restrict__ mask,
                           const float* __restrict__ mask1, __bf16* __restrict__ outb) {
  __shared__ __bf16 Ps[4][16 * 40];

  const int t = threadIdx.x, w = t >> 6, l = t & 63;
  const int c = l & 15, g = l >> 4;
  const int q0 = blockIdx.x << 4;
  const int h = (blockIdx.y << 2) + w;
  const int b = blockIdx.z;
  const size_t bh = (size_t)b * H + h;
  const __bf16* Qh = Qp + bh * S * DK;
  const __bf16* Kh = Kp + bh * S * DK;
  const __bf16* Vth = Vt + bh * DK * S;  // [64][2048]
  const float* mk_base = mask + (size_t)b * S * S;
  const float* m1_base = mask1 + (size_t)b * S * S;

  // Q fragments hoisted (NORM folded into projection)
  const bf16x8 qf0 = *(const bf16x8*)(Qh + (q0 + c) * DK + (g << 3));
  const bf16x8 qf1 = *(const bf16x8*)(Qh + (q0 + c) * DK + 32 + (g << 3));

  float mrun[4] = {-1e30f, -1e30f, -1e30f, -1e30f};
  float lrun[4] = {0.f, 0.f, 0.f, 0.f};
  f32x4 acc[4] = {};

  for (int k0 = 0; k0 < S; k0 += 32) {
    // K fragments: B-frag lane holds K[kp=kt*16+c][d=hf*32+g*8+j]
    bf16x8 kfr[2][2];
#pragma unroll
    for (int kt = 0; kt < 2; ++kt)
#pragma unroll
      for (int hf = 0; hf < 2; ++hf)
        kfr[kt][hf] = *(const bf16x8*)(Kh + (size_t)(k0 + (kt << 4) + c) * DK + (hf << 5) + (g << 3));
    // Vt fragments: B-frag lane holds V[kp=g*8+j][dv=ni*16+c] = Vt[dv][k0+g*8+j]
    bf16x8 vfr[4];
#pragma unroll
    for (int ni = 0; ni < 4; ++ni)
      vfr[ni] = *(const bf16x8*)(Vth + (size_t)((ni << 4) + c) * S + k0 + (g << 3));
    // mask tiles in C/D layout (row=g*4+r, col=kt*16+c)
    float mk[2][4], m1[2][4];
#pragma unroll
    for (int kt = 0; kt < 2; ++kt)
#pragma unroll
      for (int r = 0; r < 4; ++r) {
        size_t idx = (size_t)(q0 + (g << 2) + r) * S + (size_t)(k0 + (kt << 4) + c);
        mk[kt][r] = mk_base[idx];
        m1[kt][r] = m1_base[idx];
      }

    // QK^T: D[q=g*4+r][kp=c] per kt half
    f32x4 sc[2];
#pragma unroll
    for (int kt = 0; kt < 2; ++kt) {
      f32x4 z = {};
      z = __builtin_amdgcn_mfma_f32_16x16x32_bf16(qf0, kfr[kt][0], z, 0, 0, 0);
      z = __builtin_amdgcn_mfma_f32_16x16x32_bf16(qf1, kfr[kt][1], z, 0, 0, 0);
      sc[kt] = z;
    }

    // online softmax per q-row
    float alpha[4];
#pragma unroll
    for (int r = 0; r < 4; ++r) {
      float l0 = sc[0][r] + mk[0][r];
      float l1 = sc[1][r] + mk[1][r];
      float mx = fmaxf(l0, l1);
      mx = fmaxf(mx, __shfl_xor(mx, 1));
      mx = fmaxf(mx, __shfl_xor(mx, 2));
      mx = fmaxf(mx, __shfl_xor(mx, 4));
      mx = fmaxf(mx, __shfl_xor(mx, 8));
      float mnew = fmaxf(mrun[r], mx);
      float al = __expf(mrun[r] - mnew);
      mrun[r] = mnew;
      alpha[r] = al;
      float p0 = __expf(l0 - mnew);
      float p1 = __expf(l1 - mnew);
      float rs = p0 + p1;
      rs += __shfl_xor(rs, 1);
      rs += __shfl_xor(rs, 2);
      rs += __shfl_xor(rs, 4);
      rs += __shfl_xor(rs, 8);
      lrun[r] = lrun[r] * al + rs;  // denominator WITHOUT mask1
      Ps[w][((g << 2) + r) * 40 + c] = (__bf16)(p0 * m1[0][r]);
      Ps[w][((g << 2) + r) * 40 + 16 + c] = (__bf16)(p1 * m1[1][r]);
    }
#pragma unroll
    for (int ni = 0; ni < 4; ++ni) {
      acc[ni][0] *= alpha[0];
      acc[ni][1] *= alpha[1];
      acc[ni][2] *= alpha[2];
      acc[ni][3] *= alpha[3];
    }

    // PV: A-frag = P[q=c][kp=g*8+j] from LDS; B-frag = vfr (global-loaded)
    const bf16x8 pf = *(const bf16x8*)&Ps[w][c * 40 + (g << 3)];
#pragma unroll
    for (int ni = 0; ni < 4; ++ni)
      acc[ni] = __builtin_amdgcn_mfma_f32_16x16x32_bf16(pf, vfr[ni], acc[ni], 0, 0, 0);
  }

  float inv[4];
#pragma unroll
  for (int r = 0; r < 4; ++r) inv[r] = 1.0f / lrun[r];
  __bf16* oh = outb + bh * S * DK;
#pragma unroll
  for (int ni = 0; ni < 4; ++ni)
#pragma unroll
    for (int r = 0; r < 4; ++r)
      oh[(size_t)(q0 + (g << 2) + r) * DK + (ni << 4) + c] = (__bf16)(acc[ni][r] * inv[r]);
}

// ---------------------------------------------------------------------------
extern "C" void kernel_launch(void* const* d_in, const int* in_sizes, int n_in,
                              void* d_out, int out_size, void* d_ws, size_t ws_size,
                              hipStream_t stream) {
  (void)in_sizes; (void)n_in; (void)out_size; (void)ws_size;
  const float* q   = (const float*)d_in[0];
  const float* k   = (const float*)d_in[1];
  const float* v   = (const float*)d_in[2];
  const float* am  = (const float*)d_in[3];
  const float* am1 = (const float*)d_in[4];
  const float* wq  = (const float*)d_in[5];
  const float* bq  = (const float*)d_in[6];
  const float* wk  = (const float*)d_in[7];
  const float* bk  = (const float*)d_in[8];
  const float* wv  = (const float*)d_in[9];
  const float* bv  = (const float*)d_in[10];
  const float* wo  = (const float*)d_in[11];
  const float* bo  = (const float*)d_in[12];

  const size_t NX = (size_t)BS * D;  // 4,194,304
  const size_t NW = (size_t)D * D;   // 1,048,576

  // xq, xk live in d_out (16.8 MB fp32) until gemm_qkv completes; gemm_out
  // overwrites d_out at the very end. ws total: 8.4*5 = 42 MB.
  __bf16* xq = (__bf16*)d_out;
  __bf16* xk = xq + NX;
  char* ws = (char*)d_ws;
  __bf16* xv  = (__bf16*)ws;      // also reused as attention output Vl
  __bf16* wqb = xv + NX;
  __bf16* wkb = wqb + NW;
  __bf16* wvb = wkb + NW;
  __bf16* wob = wvb + NW;
  __bf16* Qp  = wob + NW;
  __bf16* Kp  = Qp + NX;
  __bf16* Vt  = Kp + NX;
  __bf16* Vl  = xv;               // attn output (xv dead after gemm_qkv)

  cast3<<<3 * 2048, 256, 0, stream>>>(q, k, v, xq, xk, xv);
  cast4<<<4 * 512, 256, 0, stream>>>(wq, wk, wv, wo, wqb, wkb, wvb, wob);

  dim3 gq(BS / 128, 24);  // 32 x 24 = 768 blocks
  gemm_qkv<<<gq, 512, 0, stream>>>(xq, xk, xv, wqb, wkb, wvb, bq, bk, bv, Qp, Kp, Vt);

  dim3 ga(S / 16, H / 4, BATCH);  // 1024 blocks
  attn_fused<<<ga, 256, 0, stream>>>(Qp, Kp, Vt, am, am1, Vl);

  dim3 go(BS / 128, D / 128);  // 32 x 8 = 256 blocks
  gemm_out<<<go, 512, 0, stream>>>(Vl, wob, bo, (float*)d_out);
}